// Round 7
// baseline (347.364 us; speedup 1.0000x reference)
//
#include <hip/hip_runtime.h>
#include <hip/hip_bf16.h>
#include <cstdint>

typedef __attribute__((ext_vector_type(8))) short short8;
typedef __attribute__((ext_vector_type(4))) float floatx4;
typedef __attribute__((ext_vector_type(16))) float floatx16;

#define NC   5
#define PP   196
#define DD   384
#define MM   512
#define ROWS (MM * PP)     /* 100352 = 1568 * 64 exactly */
#define NRB  1568
#define EPSN 1e-12f

/* swizzled B, 32x32x16 fragment order:
   [g 20][kk 12][f 4][lane 64][16 B], f = kh*2 + ct
   tile g = class*4 + t covers class-local cols t*64 + ct*32 + (lane&31), k = kk*32 + kh*16 + (lane>>5)*8 + j.
   cols >= 196 replicate col 195 (max-invariant). Padded to 24 tiles for branchless prefetch overrun. */
#define TILE_BYTES  49152   /* 12 * 4096 */
#define KSTEP_BYTES 4096
#define SNW_ALLOC   (24 * TILE_BYTES)   /* 1179648 */

/* monotone float <-> uint encoding so atomicMax(unsigned) orders like float */
__device__ __forceinline__ unsigned enc_f(float f) {
    unsigned u = __float_as_uint(f);
    return (u & 0x80000000u) ? ~u : (u | 0x80000000u);
}
__device__ __forceinline__ float dec_f(unsigned u) {
    unsigned b = (u & 0x80000000u) ? (u ^ 0x80000000u) : ~u;
    return __uint_as_float(b);
}
#define ENC_NEG_INF 0x007FFFFFu

/* ---- pass 1a: 1/||support_row|| (980 rows) ---- */
__global__ __launch_bounds__(256) void k_norm0(const float* __restrict__ sup,
                                               float* __restrict__ sinv) {
    int wid = threadIdx.x >> 6, lane = threadIdx.x & 63;
    int r = blockIdx.x * 4 + wid;
    if (r >= NC * PP) return;
    const float* src = sup + (size_t)r * DD;
    float s = 0.f;
    #pragma unroll
    for (int j = 0; j < 6; ++j) { float v = src[lane + j * 64]; s += v * v; }
    #pragma unroll
    for (int off = 1; off < 64; off <<= 1) s += __shfl_xor(s, off, 64);
    if (lane == 0) sinv[r] = 1.0f / fmaxf(sqrtf(s), EPSN);
}

/* ---- pass 1b: normalize + swizzle support into 32x32x16 B-fragment order ---- */
__global__ __launch_bounds__(256) void k_swz(const float* __restrict__ sup,
                                             const float* __restrict__ sinv,
                                             __hip_bfloat16* __restrict__ snw) {
    int s = blockIdx.x * 256 + threadIdx.x;        /* 61440 slices of 16 B */
    int lane = s & 63;
    int f = (s >> 6) & 3;
    int t1 = s >> 8;                               /* 0..239 */
    int kk = t1 % 12;
    int g  = t1 / 12;                              /* class*4 + t */
    int kh = f >> 1, ct = f & 1;
    int l31 = lane & 31, lh = lane >> 5;
    int cl = (g & 3) * 64 + ct * 32 + l31;         /* class-local padded col */
    if (cl > PP - 1) cl = PP - 1;                  /* replicate last col */
    int srow = (g >> 2) * PP + cl;
    const float* sp = sup + (size_t)srow * DD + kk * 32 + kh * 16 + lh * 8;
    float inv = sinv[srow];
    alignas(16) __hip_bfloat16 hb[8];
    #pragma unroll
    for (int e = 0; e < 8; ++e) hb[e] = __float2bfloat16(sp[e] * inv);
    *(uint4*)((char*)snw + (size_t)s * 16) = *(const uint4*)hb;
}

/* ---- main: one block per 64-row strip; A in LDS in 32x32x16 fragment order;
        waves stream B from L2 (pre-swizzled), depth-3 branchless pipeline,
        NO barriers in the main loop ---- */
__global__ __launch_bounds__(256, 3) void k_gemm_max(const float* __restrict__ q,
                                                     const __hip_bfloat16* __restrict__ snw,
                                                     float* __restrict__ rowmaxg) {
    /* As: [kk 12][kh 2][rt 2][lane 64][8 bf16] = 49152 B */
    __shared__ __hip_bfloat16 As[12 * 2 * 2 * 64 * 8];
    __shared__ unsigned rmax[64 * NC];
    __shared__ float rss[64];

    const int tid  = threadIdx.x;
    const int row0 = blockIdx.x * 64;
    const int lane = tid & 63;
    const int wav  = tid >> 6;

    for (int i = tid; i < 64 * NC; i += 256) rmax[i] = ENC_NEG_INF;

    /* ---- A staging: fp32 -> bf16 -> LDS 32x32 fragment slots; fused row sumsq.
            Thread (arow=tid>>2, asub=tid&3): kh=asub>>1, lh=asub&1 fixed; kk=i. */
    {
        const int arow = tid >> 2;
        const int asub = tid & 3;
        const int r32  = arow & 31, rt = arow >> 5;
        const int kh   = asub >> 1, lh = asub & 1;
        const float* src = q + (size_t)(row0 + arow) * DD;
        float ss = 0.f;
        #pragma unroll
        for (int i = 0; i < 12; ++i) {
            int ch = asub + i * 4;
            const floatx4* p = (const floatx4*)(src + ch * 8);
            floatx4 x0 = __builtin_nontemporal_load(p);
            floatx4 x1 = __builtin_nontemporal_load(p + 1);
            ss += x0.x*x0.x + x0.y*x0.y + x0.z*x0.z + x0.w*x0.w
                + x1.x*x1.x + x1.y*x1.y + x1.z*x1.z + x1.w*x1.w;
            alignas(16) __hip_bfloat16 hb[8];
            hb[0] = __float2bfloat16(x0.x); hb[1] = __float2bfloat16(x0.y);
            hb[2] = __float2bfloat16(x0.z); hb[3] = __float2bfloat16(x0.w);
            hb[4] = __float2bfloat16(x1.x); hb[5] = __float2bfloat16(x1.y);
            hb[6] = __float2bfloat16(x1.z); hb[7] = __float2bfloat16(x1.w);
            int idx = ((i * 2 + kh) * 2 + rt) * 64 + lh * 32 + r32;
            *(uint4*)&As[idx * 8] = *(const uint4*)hb;
        }
        ss += __shfl_xor(ss, 1, 64);
        ss += __shfl_xor(ss, 2, 64);
        if (asub == 0) rss[arow] = ss;
    }
    __syncthreads();                            /* the ONLY barrier before the epilogue */

    /* ---- 20 col-tiles (class = g>>2), 5 per wave; depth-3 rotating B buffers,
            branchless cross-tile prefetch (snw padded to 24 tiles).
            kk loop stays rolled: full unroll spilled to scratch in R3. ---- */
    const char* bbase = (const char*)snw + (size_t)wav * TILE_BYTES + (size_t)lane * 16;
    short8 b0[4], b1[4], b2[4];
    #pragma unroll
    for (int f = 0; f < 4; ++f) b0[f] = *(const short8*)(bbase + 0 * KSTEP_BYTES + f * 1024);
    #pragma unroll
    for (int f = 0; f < 4; ++f) b1[f] = *(const short8*)(bbase + 1 * KSTEP_BYTES + f * 1024);
    #pragma unroll
    for (int f = 0; f < 4; ++f) b2[f] = *(const short8*)(bbase + 2 * KSTEP_BYTES + f * 1024);

    /* prefetch for kk-step nk (nk may overrun into next tile; garbage ok, never consumed) */
    #define PREF(buf, nk_)                                                           \
        do {                                                                         \
            int nk = (nk_);                                                          \
            size_t off = (size_t)nk * KSTEP_BYTES + (nk >= 12 ? 3 * TILE_BYTES : 0); \
            _Pragma("unroll")                                                        \
            for (int f = 0; f < 4; ++f)                                              \
                buf[f] = *(const short8*)(bbase + off + f * 1024);                   \
        } while (0)

    #define STEP(buf, kka)                                                           \
        do {                                                                         \
            int kx = (kka);                                                          \
            short8 a00 = *(const short8*)&As[(((kx*2+0)*2+0)*64 + lane) * 8];         \
            short8 a01 = *(const short8*)&As[(((kx*2+0)*2+1)*64 + lane) * 8];         \
            short8 a10 = *(const short8*)&As[(((kx*2+1)*2+0)*64 + lane) * 8];         \
            short8 a11 = *(const short8*)&As[(((kx*2+1)*2+1)*64 + lane) * 8];         \
            acc[0][0] = __builtin_amdgcn_mfma_f32_32x32x16_bf16(a00, buf[0], acc[0][0], 0, 0, 0); \
            acc[0][1] = __builtin_amdgcn_mfma_f32_32x32x16_bf16(a00, buf[1], acc[0][1], 0, 0, 0); \
            acc[1][0] = __builtin_amdgcn_mfma_f32_32x32x16_bf16(a01, buf[0], acc[1][0], 0, 0, 0); \
            acc[1][1] = __builtin_amdgcn_mfma_f32_32x32x16_bf16(a01, buf[1], acc[1][1], 0, 0, 0); \
            acc[0][0] = __builtin_amdgcn_mfma_f32_32x32x16_bf16(a10, buf[2], acc[0][0], 0, 0, 0); \
            acc[0][1] = __builtin_amdgcn_mfma_f32_32x32x16_bf16(a10, buf[3], acc[0][1], 0, 0, 0); \
            acc[1][0] = __builtin_amdgcn_mfma_f32_32x32x16_bf16(a11, buf[2], acc[1][0], 0, 0, 0); \
            acc[1][1] = __builtin_amdgcn_mfma_f32_32x32x16_bf16(a11, buf[3], acc[1][1], 0, 0, 0); \
        } while (0)

    #pragma unroll 1
    for (int g = wav; g < 20; g += 4) {
        floatx16 acc[2][2];
        #pragma unroll
        for (int i = 0; i < 2; ++i)
            #pragma unroll
            for (int j = 0; j < 2; ++j)
                #pragma unroll
                for (int e = 0; e < 16; ++e) acc[i][j][e] = 0.f;

        #pragma unroll 1
        for (int kk = 0; kk < 12; kk += 3) {
            STEP(b0, kk);     PREF(b0, kk + 3);
            STEP(b1, kk + 1); PREF(b1, kk + 4);
            STEP(b2, kk + 2); PREF(b2, kk + 5);
        }

        /* ---- epilogue: col-max. C/D: col=lane&31, row=(reg&3)+8*(reg>>2)+4*(lane>>5).
                3 shfl steps fold cols to groups of 8; LDS atomicMax merges the rest. */
        const int c = g >> 2;
        const int h = lane >> 5;
        #pragma unroll
        for (int rt = 0; rt < 2; ++rt) {
            #pragma unroll
            for (int reg = 0; reg < 16; ++reg) {
                float m = fmaxf(acc[rt][0][reg], acc[rt][1][reg]);
                m = fmaxf(m, __shfl_xor(m, 1, 64));
                m = fmaxf(m, __shfl_xor(m, 2, 64));
                m = fmaxf(m, __shfl_xor(m, 4, 64));
                if ((lane & 7) == 0) {
                    int row = rt * 32 + (reg & 3) + 8 * (reg >> 2) + 4 * h;
                    atomicMax(&rmax[row * NC + c], enc_f(m));
                }
            }
        }
        bbase += 4 * TILE_BYTES;
    }

    __syncthreads();
    /* rowmaxg layout [c][row] -> coalesced stores here, coalesced loads in k_top6 */
    for (int i = tid; i < 64 * NC; i += 256) {
        int c = i >> 6, row = i & 63;
        float inv = 1.0f / fmaxf(sqrtf(rss[row]), EPSN);
        __builtin_nontemporal_store(dec_f(rmax[row * NC + c]) * inv,
                                    &rowmaxg[(size_t)c * ROWS + row0 + row]);
    }
}

/* ---- top-6 sum per (m, c): one wave each ---- */
__global__ __launch_bounds__(256) void k_top6(const float* __restrict__ rowmaxg,
                                              const float* __restrict__ scale,
                                              const float* __restrict__ bias,
                                              float* __restrict__ out) {
    int wav = threadIdx.x >> 6, lane = threadIdx.x & 63;
    int pair = blockIdx.x * 4 + wav;
    if (pair >= MM * NC) return;
    int m = pair / NC, c = pair % NC;
    size_t base = (size_t)c * ROWS + (size_t)m * PP;
    float v[4];
    #pragma unroll
    for (int i = 0; i < 4; ++i) {
        int p = lane + i * 64;
        v[i] = (p < PP) ? rowmaxg[base + p] : -INFINITY;
    }
    float sum = 0.f;
    for (int t = 0; t < 6; ++t) {
        float bv = v[0]; int bi = 0;
        #pragma unroll
        for (int i = 1; i < 4; ++i) { if (v[i] > bv) { bv = v[i]; bi = i; } }
        int gid = bi * 64 + lane;
        #pragma unroll
        for (int off = 1; off < 64; off <<= 1) {
            float ov = __shfl_xor(bv, off, 64);
            int og  = __shfl_xor(gid, off, 64);
            if (ov > bv || (ov == bv && og < gid)) { bv = ov; gid = og; }
        }
        sum += bv;
        if ((gid & 63) == lane) v[gid >> 6] = -INFINITY;  /* kill exactly one */
    }
    if (lane == 0) out[pair] = scale[0] * (sum + bias[0]);
}

extern "C" void kernel_launch(void* const* d_in, const int* in_sizes, int n_in,
                              void* d_out, int out_size, void* d_ws, size_t ws_size,
                              hipStream_t stream) {
    const float* support = (const float*)d_in[0];
    const float* query   = (const float*)d_in[1];
    const float* scale   = (const float*)d_in[2];
    const float* bias    = (const float*)d_in[3];
    float* out = (float*)d_out;

    char* ws = (char*)d_ws;
    __hip_bfloat16* snw = (__hip_bfloat16*)ws;                 /* 24 tiles = 1179648 B (20 used + overrun pad) */
    float* sinv         = (float*)(ws + SNW_ALLOC);            /* 980*4 -> pad 4096 */
    float* rowmaxg      = (float*)(ws + SNW_ALLOC + 4096);     /* 5*100352*4 = 2007040 */

    hipLaunchKernelGGL(k_norm0,   dim3(245),  dim3(256), 0, stream, support, sinv);
    hipLaunchKernelGGL(k_swz,     dim3(240),  dim3(256), 0, stream, support, sinv, snw);
    hipLaunchKernelGGL(k_gemm_max,dim3(NRB),  dim3(256), 0, stream, query, snw, rowmaxg);
    hipLaunchKernelGGL(k_top6,    dim3(640),  dim3(256), 0, stream, rowmaxg, scale, bias, out);
}